// Round 5
// baseline (801.579 us; speedup 1.0000x reference)
//
#include <hip/hip_runtime.h>
#include <hip/hip_fp16.h>
#include <math.h>

// GAT 2-layer forward on MI355X.
// CSR build via bucketed counting sort (bucket = dst>>7), then per layer:
//   gemm_alpha: h = x@W; x-row via SCALAR loads, 8 indep fma chains, h in FP16
//   aggregate:  wave = 2 dst nodes, lane = channel-pair (__half2 gathers),
//               online-softmax weighted sum, fused epilogue.

constexpr int FDIM = 64;

// ---------------- CSR build (bucketed counting sort) ----------------
// Bucket b = dst >> 7 (128 nodes/bucket). Packed edge: (src<<7)|(dst&127).

__global__ void bhist_kernel(const int* __restrict__ ei, int E, int Etot,
                             int* __restrict__ bhist) {
  int i = blockIdx.x * blockDim.x + threadIdx.x;
  int stride = gridDim.x * blockDim.x;
  for (; i < Etot; i += stride) {
    int dst = (i < E) ? ei[E + i] : (i - E);   // self-loops appended
    atomicAdd(&bhist[dst >> 7], 1);
  }
}

__global__ __launch_bounds__(1024) void bscan_kernel(
    const int* __restrict__ bhist, int NB, int Etot,
    int* __restrict__ boff, int* __restrict__ bcur) {
  int t = threadIdx.x;
  int v = (t < NB) ? bhist[t] : 0;
  int lane = t & 63, w = t >> 6;
  int x = v;
#pragma unroll
  for (int off = 1; off < 64; off <<= 1) {
    int u = __shfl_up(x, off, 64);
    if (lane >= off) x += u;
  }
  __shared__ int wsum[16];
  if (lane == 63) wsum[w] = x;
  __syncthreads();
  int add = 0;
#pragma unroll
  for (int k = 0; k < 16; ++k) add += (k < w) ? wsum[k] : 0;
  int incl = x + add;
  if (t < NB) {
    boff[t] = incl - v;
    bcur[t] = incl - v;
    if (t == NB - 1) boff[NB] = incl;
  }
}

__global__ void bscatter_kernel(const int* __restrict__ ei, int E, int Etot,
                                int* __restrict__ bcur,
                                unsigned* __restrict__ bpacked) {
  int i = blockIdx.x * blockDim.x + threadIdx.x;
  int stride = gridDim.x * blockDim.x;
  for (; i < Etot; i += stride) {
    int src, dst;
    if (i < E) { src = ei[i]; dst = ei[E + i]; }
    else       { src = i - E; dst = i - E; }
    int pos = atomicAdd(&bcur[dst >> 7], 1);
    bpacked[pos] = ((unsigned)src << 7) | (unsigned)(dst & 127);
  }
}

// One workgroup per bucket: LDS histogram of 128 dst slots, wave scan,
// write row_start slice, bucket-local scatter of esrc.
__global__ __launch_bounds__(256) void bucket_csr_kernel(
    const unsigned* __restrict__ bpacked, const int* __restrict__ boff,
    int N, int NB, int Etot,
    int* __restrict__ row_start, int* __restrict__ esrc) {
  __shared__ int hist[128];
  __shared__ int excl[128];
  __shared__ int cur[128];
  int b = blockIdx.x;
  int t = threadIdx.x;
  int base = boff[b];
  int end = boff[b + 1];
  if (t < 128) hist[t] = 0;
  __syncthreads();
  for (int i = base + t; i < end; i += 256)
    atomicAdd(&hist[bpacked[i] & 127u], 1);
  __syncthreads();
  if (t < 64) {  // wave 0 scans both 64-halves
    int v0 = hist[t], v1 = hist[64 + t];
    int x0 = v0;
#pragma unroll
    for (int off = 1; off < 64; off <<= 1) {
      int u = __shfl_up(x0, off, 64);
      if (t >= off) x0 += u;
    }
    int tot0 = __shfl(x0, 63, 64);
    int x1 = v1;
#pragma unroll
    for (int off = 1; off < 64; off <<= 1) {
      int u = __shfl_up(x1, off, 64);
      if (t >= off) x1 += u;
    }
    excl[t] = x0 - v0;
    excl[64 + t] = tot0 + x1 - v1;
    cur[t] = x0 - v0;
    cur[64 + t] = tot0 + x1 - v1;
  }
  __syncthreads();
  int node0 = b << 7;
  if (t < 128 && node0 + t < N) row_start[node0 + t] = base + excl[t];
  if (b == NB - 1 && t == 0) row_start[N] = Etot;
  for (int i = base + t; i < end; i += 256) {
    unsigned p = bpacked[i];
    int pos = base + atomicAdd(&cur[p & 127u], 1);
    esrc[pos] = (int)(p >> 7);
  }
}

// ---------------- GEMM (x @ W) + attention logits ----------------
// Grid-stride waves; W column (64 floats) in VGPRs. Row index forced scalar
// (readfirstlane) so x-row elements come from s_load (scalar pipe).
// 2 rows/iter x 4 accumulators = 8 independent fma chains.

template <int HEADS>
__global__ __launch_bounds__(256) void gemm_alpha_kernel(
    const float* __restrict__ X, const float* __restrict__ W,
    const float* __restrict__ a_s, const float* __restrict__ a_d, int N,
    __half* __restrict__ H, float* __restrict__ AS, float* __restrict__ AD) {
  int lane = threadIdx.x & 63;
  int gwave = (blockIdx.x * 256 + threadIdx.x) >> 6;
  int nwaves = gridDim.x * 4;

  float w[FDIM];
#pragma unroll
  for (int k = 0; k < FDIM; ++k) w[k] = W[k * FDIM + lane];
  float as_l = a_s[lane];
  float ad_l = a_d[lane];
  constexpr int G = 64 / HEADS;

  for (int n = gwave * 2; n < N; n += nwaves * 2) {
    int nu = __builtin_amdgcn_readfirstlane(n);
    const float* xa = X + (size_t)nu * FDIM;
    bool twob = (nu + 1) < N;
    const float* xb = twob ? (xa + FDIM) : xa;

    float a0 = 0.f, a1 = 0.f, a2 = 0.f, a3 = 0.f;
    float c0 = 0.f, c1 = 0.f, c2 = 0.f, c3 = 0.f;
#pragma unroll
    for (int k = 0; k < FDIM; k += 4) {
      a0 = fmaf(xa[k + 0], w[k + 0], a0);
      a1 = fmaf(xa[k + 1], w[k + 1], a1);
      a2 = fmaf(xa[k + 2], w[k + 2], a2);
      a3 = fmaf(xa[k + 3], w[k + 3], a3);
      c0 = fmaf(xb[k + 0], w[k + 0], c0);
      c1 = fmaf(xb[k + 1], w[k + 1], c1);
      c2 = fmaf(xb[k + 2], w[k + 2], c2);
      c3 = fmaf(xb[k + 3], w[k + 3], c3);
    }
    float ha = (a0 + a1) + (a2 + a3);
    float hb = (c0 + c1) + (c2 + c3);

    H[(size_t)nu * FDIM + lane] = __float2half(ha);
    if (twob) H[(size_t)(nu + 1) * FDIM + lane] = __float2half(hb);

    float tsa = ha * as_l, tda = ha * ad_l;
    float tsb = hb * as_l, tdb = hb * ad_l;
#pragma unroll
    for (int off = 1; off < G; off <<= 1) {
      tsa += __shfl_xor(tsa, off, 64);
      tda += __shfl_xor(tda, off, 64);
      tsb += __shfl_xor(tsb, off, 64);
      tdb += __shfl_xor(tdb, off, 64);
    }
    if ((lane & (G - 1)) == 0) {
      int head = lane / G;
      AS[(size_t)nu * HEADS + head] = tsa;
      AD[(size_t)nu * HEADS + head] = tda;
      if (twob) {
        AS[(size_t)(nu + 1) * HEADS + head] = tsb;
        AD[(size_t)(nu + 1) * HEADS + head] = tdb;
      }
    }
  }
}

// ---------------- online-softmax aggregation ----------------
// Wave = 2 dst nodes (lanes 0-31 node A, lanes 32-63 node B).
// Lane owns channel pair (2c, 2c+1), gathered as __half2; accumulate fp32.
// FINAL=false: fuse +bias, ELU.  FINAL=true: fuse +bias, row L2-normalize.

template <int HEADS, bool FINAL>
__global__ __launch_bounds__(256) void aggregate_kernel(
    const int* __restrict__ row_start, const int* __restrict__ esrc,
    const __half* __restrict__ H, const float* __restrict__ AS,
    const float* __restrict__ AD, const float* __restrict__ bias, int N,
    float* __restrict__ OUT) {
  int t = threadIdx.x;
  int wid = t >> 6;
  int half = (t >> 5) & 1;
  int ll = t & 31;                       // lane within half-wave
  int n = blockIdx.x * 8 + wid * 2 + half;

  constexpr int G = 64 / HEADS;          // channels per head
  int head = (2 * ll) / G;               // both channels in same head (G>=2)

  int rs = 0, re = 0;
  float ad = 0.f;
  if (n < N) {
    rs = row_start[n];
    re = row_start[n + 1];
    ad = AD[(size_t)n * HEADS + head];
  }
  int deg = re - rs;
  int degO = __shfl_xor(deg, 32, 64);    // other half's degree
  int degmax = max(deg, degO);

  const __half2* H2 = reinterpret_cast<const __half2*>(H);

  float m = -1e30f, denom = 0.f, ax = 0.f, ay = 0.f;
  for (int i = 0; i < degmax; ++i) {
    if (i < deg) {
      int s = esrc[rs + i];
      float e = AS[(unsigned)s * HEADS + head] + ad;
      e = e > 0.f ? e : 0.2f * e;
      float2 hf = __half22float2(H2[(unsigned)s * 32u + (unsigned)ll]);
      float mn = fmaxf(m, e);
      float sc = __expf(m - mn);
      float wg = __expf(e - mn);
      denom = fmaf(denom, sc, wg);
      ax = fmaf(ax, sc, wg * hf.x);
      ay = fmaf(ay, sc, wg * hf.y);
      m = mn;
    }
  }

  if (n >= N) return;

  float2 b2 = reinterpret_cast<const float2*>(bias)[ll];
  float inv = 1.f / (denom + 1e-16f);
  float vx = ax * inv + b2.x;
  float vy = ay * inv + b2.y;
  float2* OUT2 = reinterpret_cast<float2*>(OUT);
  if (FINAL) {
    float ss = vx * vx + vy * vy;
#pragma unroll
    for (int off = 1; off < 32; off <<= 1) ss += __shfl_xor(ss, off, 32);
    float rn = 1.f / fmaxf(sqrtf(ss), 1e-12f);
    OUT2[(size_t)n * 32 + ll] = make_float2(vx * rn, vy * rn);
  } else {
    vx = vx > 0.f ? vx : expm1f(vx);
    vy = vy > 0.f ? vy : expm1f(vy);
    OUT2[(size_t)n * 32 + ll] = make_float2(vx, vy);
  }
}

// ---------------- launch ----------------

extern "C" void kernel_launch(void* const* d_in, const int* in_sizes, int n_in,
                              void* d_out, int out_size, void* d_ws,
                              size_t ws_size, hipStream_t stream) {
  const int* ei = (const int*)d_in[0];          // [2, E]
  const float* emb = (const float*)d_in[1];     // [N, 64]
  const float* W1 = (const float*)d_in[2];
  const float* as1 = (const float*)d_in[3];
  const float* ad1 = (const float*)d_in[4];
  const float* b1 = (const float*)d_in[5];
  const float* W2 = (const float*)d_in[6];
  const float* as2 = (const float*)d_in[7];
  const float* ad2 = (const float*)d_in[8];
  const float* b2 = (const float*)d_in[9];
  float* out = (float*)d_out;

  int E = in_sizes[0] / 2;
  int N = in_sizes[1] / FDIM;
  int Etot = E + N;
  int NB = (N + 127) >> 7;   // buckets of 128 nodes (<=1024 for bscan)

  char* ws = (char*)d_ws;
  size_t off = 0;
  auto alloc = [&](size_t bytes) -> void* {
    void* p = ws + off;
    off += (bytes + 255) & ~(size_t)255;
    return p;
  };
  int* bhist = (int*)alloc((size_t)NB * sizeof(int));
  int* boff = (int*)alloc((size_t)(NB + 1) * sizeof(int));
  int* bcur = (int*)alloc((size_t)NB * sizeof(int));
  unsigned* bpacked = (unsigned*)alloc((size_t)Etot * sizeof(unsigned));
  int* row_start = (int*)alloc((size_t)(N + 1) * sizeof(int));
  int* esrc = (int*)alloc((size_t)Etot * sizeof(int));
  __half* hbuf = (__half*)alloc((size_t)N * FDIM * sizeof(__half));
  float* xbuf = (float*)alloc((size_t)N * FDIM * sizeof(float));
  float* AS = (float*)alloc((size_t)N * 4 * sizeof(float));
  float* AD = (float*)alloc((size_t)N * 4 * sizeof(float));

  hipMemsetAsync(bhist, 0, (size_t)NB * sizeof(int), stream);
  bhist_kernel<<<1024, 256, 0, stream>>>(ei, E, Etot, bhist);
  bscan_kernel<<<1, 1024, 0, stream>>>(bhist, NB, Etot, boff, bcur);
  bscatter_kernel<<<1024, 256, 0, stream>>>(ei, E, Etot, bcur, bpacked);
  bucket_csr_kernel<<<NB, 256, 0, stream>>>(bpacked, boff, N, NB, Etot,
                                            row_start, esrc);

  int ga = (N + 7) / 8;  // aggregate: 8 nodes per block (4 waves x 2)
  // Layer 1: GATConv(64 -> 16, heads=4, concat) + bias + ELU
  gemm_alpha_kernel<4><<<2048, 256, 0, stream>>>(emb, W1, as1, ad1, N, hbuf, AS, AD);
  aggregate_kernel<4, false><<<ga, 256, 0, stream>>>(row_start, esrc, hbuf, AS, AD, b1, N, xbuf);
  // Layer 2: GATConv(64 -> 64, heads=1) + bias + L2 normalize
  gemm_alpha_kernel<1><<<2048, 256, 0, stream>>>(xbuf, W2, as2, ad2, N, hbuf, AS, AD);
  aggregate_kernel<1, true><<<ga, 256, 0, stream>>>(row_start, esrc, hbuf, AS, AD, b2, N, out);
}

// Round 6
// 266.998 us; speedup vs baseline: 3.0022x; 3.0022x over previous
//
#include <hip/hip_runtime.h>
#include <hip/hip_fp16.h>
#include <math.h>

// GAT 2-layer forward on MI355X.
// CSR build: tile-binned counting sort. Buckets of 512 dst nodes; per-edge
// atomics are LDS-only; global atomics are block-aggregated reservations.
// Then per layer:
//   gemm_alpha: h = x@W; x-row via SCALAR loads, 8 indep fma chains, h in FP16
//   aggregate:  wave = 2 dst nodes, lane = channel-pair (__half2 gathers),
//               online-softmax weighted sum, fused epilogue.

constexpr int FDIM = 64;
constexpr int BSHIFT = 9;                 // 512 nodes per bucket
constexpr int BMASK = (1 << BSHIFT) - 1;  // 511
constexpr int EDGE_TILE = 4096;           // edges per phase-A block

// ---------------- CSR build ----------------

// Phase A1: block-aggregated bucket histogram.
__global__ __launch_bounds__(256) void tile_hist_kernel(
    const int* __restrict__ ei, int E, int Etot, int NB,
    int* __restrict__ gbhist) {
  __shared__ int hist[512];
  int t = threadIdx.x;
  for (int b = t; b < NB; b += 256) hist[b] = 0;
  __syncthreads();
  int i0 = blockIdx.x * EDGE_TILE;
  int iend = min(i0 + EDGE_TILE, Etot);
  for (int i = i0 + t; i < iend; i += 256) {
    int dst = (i < E) ? ei[E + i] : (i - E);  // self-loops appended
    atomicAdd(&hist[dst >> BSHIFT], 1);
  }
  __syncthreads();
  for (int b = t; b < NB; b += 256)
    if (hist[b]) atomicAdd(&gbhist[b], hist[b]);
}

// Exclusive scan of NB (<=1024) bucket totals -> boff, bcur.
__global__ __launch_bounds__(256) void bscan_kernel(
    const int* __restrict__ gbhist, int NB, int Etot,
    int* __restrict__ boff, int* __restrict__ bcur) {
  int t = threadIdx.x;
  int v = (t < NB) ? gbhist[t] : 0;
  int lane = t & 63, w = t >> 6;
  int x = v;
#pragma unroll
  for (int off = 1; off < 64; off <<= 1) {
    int u = __shfl_up(x, off, 64);
    if (lane >= off) x += u;
  }
  __shared__ int wsum[4];
  if (lane == 63) wsum[w] = x;
  __syncthreads();
  int add = 0;
#pragma unroll
  for (int k = 0; k < 4; ++k) add += (k < w) ? wsum[k] : 0;
  int incl = x + add;
  if (t < NB) {
    boff[t] = incl - v;
    bcur[t] = incl - v;
  }
  if (t == 0) boff[NB] = Etot;
}

// Phase A2: re-histogram tile, reserve per-bucket chunks (1 global atomic per
// block x bucket), scatter packed edges via LDS cursors.
__global__ __launch_bounds__(256) void tile_scatter_kernel(
    const int* __restrict__ ei, int E, int Etot, int NB,
    int* __restrict__ bcur, unsigned* __restrict__ bpacked) {
  __shared__ int hist[512];
  __shared__ int cur[512];
  int t = threadIdx.x;
  for (int b = t; b < NB; b += 256) hist[b] = 0;
  __syncthreads();
  int i0 = blockIdx.x * EDGE_TILE;
  int iend = min(i0 + EDGE_TILE, Etot);
  for (int i = i0 + t; i < iend; i += 256) {
    int dst = (i < E) ? ei[E + i] : (i - E);
    atomicAdd(&hist[dst >> BSHIFT], 1);
  }
  __syncthreads();
  for (int b = t; b < NB; b += 256)
    cur[b] = hist[b] ? atomicAdd(&bcur[b], hist[b]) : 0;
  __syncthreads();
  for (int i = i0 + t; i < iend; i += 256) {
    int src, dst;
    if (i < E) { src = ei[i]; dst = ei[E + i]; }
    else       { src = i - E; dst = i - E; }
    int pos = atomicAdd(&cur[dst >> BSHIFT], 1);
    bpacked[pos] = ((unsigned)src << BSHIFT) | (unsigned)(dst & BMASK);
  }
}

// Phase B: one workgroup per bucket. LDS hist over 512 node slots, block scan,
// row_start slice, bucket-local esrc scatter.
__global__ __launch_bounds__(256) void bucket_csr_kernel(
    const unsigned* __restrict__ bpacked, const int* __restrict__ boff,
    int N, int NB, int Etot,
    int* __restrict__ row_start, int* __restrict__ esrc) {
  __shared__ int hist[512];
  __shared__ int excl[512];
  __shared__ int cur[512];
  int b = blockIdx.x;
  int t = threadIdx.x;
  int base = boff[b];
  int end = boff[b + 1];
  hist[t] = 0;
  hist[256 + t] = 0;
  __syncthreads();
  for (int i = base + t; i < end; i += 256)
    atomicAdd(&hist[bpacked[i] & (unsigned)BMASK], 1);
  __syncthreads();
  // Block scan over 512 slots: thread t owns slots 2t, 2t+1.
  int h0 = hist[2 * t], h1 = hist[2 * t + 1];
  int s = h0 + h1;
  int lane = t & 63, w = t >> 6;
  int x = s;
#pragma unroll
  for (int off = 1; off < 64; off <<= 1) {
    int u = __shfl_up(x, off, 64);
    if (lane >= off) x += u;
  }
  __shared__ int wsum[4];
  if (lane == 63) wsum[w] = x;
  __syncthreads();
  int add = 0;
#pragma unroll
  for (int k = 0; k < 4; ++k) add += (k < w) ? wsum[k] : 0;
  int e0 = x + add - s;  // exclusive prefix for slot 2t
  excl[2 * t] = e0;
  excl[2 * t + 1] = e0 + h0;
  cur[2 * t] = e0;
  cur[2 * t + 1] = e0 + h0;
  __syncthreads();
  int node0 = b << BSHIFT;
#pragma unroll
  for (int k = 0; k < 2; ++k) {
    int slot = k * 256 + t;
    int node = node0 + slot;
    if (node < N) row_start[node] = base + excl[slot];
  }
  if (b == NB - 1 && t == 0) row_start[N] = Etot;
  for (int i = base + t; i < end; i += 256) {
    unsigned p = bpacked[i];
    int pos = base + atomicAdd(&cur[p & (unsigned)BMASK], 1);
    esrc[pos] = (int)(p >> BSHIFT);
  }
}

// ---------------- GEMM (x @ W) + attention logits ----------------
// Grid-stride waves; W column (64 floats) in VGPRs. Row index forced scalar
// (readfirstlane) so x-row elements come from s_load (scalar pipe).
// 2 rows/iter x 4 accumulators = 8 independent fma chains.

template <int HEADS>
__global__ __launch_bounds__(256) void gemm_alpha_kernel(
    const float* __restrict__ X, const float* __restrict__ W,
    const float* __restrict__ a_s, const float* __restrict__ a_d, int N,
    __half* __restrict__ H, float* __restrict__ AS, float* __restrict__ AD) {
  int lane = threadIdx.x & 63;
  int gwave = (blockIdx.x * 256 + threadIdx.x) >> 6;
  int nwaves = gridDim.x * 4;

  float w[FDIM];
#pragma unroll
  for (int k = 0; k < FDIM; ++k) w[k] = W[k * FDIM + lane];
  float as_l = a_s[lane];
  float ad_l = a_d[lane];
  constexpr int G = 64 / HEADS;

  for (int n = gwave * 2; n < N; n += nwaves * 2) {
    int nu = __builtin_amdgcn_readfirstlane(n);
    const float* xa = X + (size_t)nu * FDIM;
    bool twob = (nu + 1) < N;
    const float* xb = twob ? (xa + FDIM) : xa;

    float a0 = 0.f, a1 = 0.f, a2 = 0.f, a3 = 0.f;
    float c0 = 0.f, c1 = 0.f, c2 = 0.f, c3 = 0.f;
#pragma unroll
    for (int k = 0; k < FDIM; k += 4) {
      a0 = fmaf(xa[k + 0], w[k + 0], a0);
      a1 = fmaf(xa[k + 1], w[k + 1], a1);
      a2 = fmaf(xa[k + 2], w[k + 2], a2);
      a3 = fmaf(xa[k + 3], w[k + 3], a3);
      c0 = fmaf(xb[k + 0], w[k + 0], c0);
      c1 = fmaf(xb[k + 1], w[k + 1], c1);
      c2 = fmaf(xb[k + 2], w[k + 2], c2);
      c3 = fmaf(xb[k + 3], w[k + 3], c3);
    }
    float ha = (a0 + a1) + (a2 + a3);
    float hb = (c0 + c1) + (c2 + c3);

    H[(size_t)nu * FDIM + lane] = __float2half(ha);
    if (twob) H[(size_t)(nu + 1) * FDIM + lane] = __float2half(hb);

    float tsa = ha * as_l, tda = ha * ad_l;
    float tsb = hb * as_l, tdb = hb * ad_l;
#pragma unroll
    for (int off = 1; off < G; off <<= 1) {
      tsa += __shfl_xor(tsa, off, 64);
      tda += __shfl_xor(tda, off, 64);
      tsb += __shfl_xor(tsb, off, 64);
      tdb += __shfl_xor(tdb, off, 64);
    }
    if ((lane & (G - 1)) == 0) {
      int head = lane / G;
      AS[(size_t)nu * HEADS + head] = tsa;
      AD[(size_t)nu * HEADS + head] = tda;
      if (twob) {
        AS[(size_t)(nu + 1) * HEADS + head] = tsb;
        AD[(size_t)(nu + 1) * HEADS + head] = tdb;
      }
    }
  }
}

// ---------------- online-softmax aggregation ----------------
// Wave = 2 dst nodes (lanes 0-31 node A, lanes 32-63 node B).
// Lane owns channel pair (2c, 2c+1), gathered as __half2; accumulate fp32.
// FINAL=false: fuse +bias, ELU.  FINAL=true: fuse +bias, row L2-normalize.

template <int HEADS, bool FINAL>
__global__ __launch_bounds__(256) void aggregate_kernel(
    const int* __restrict__ row_start, const int* __restrict__ esrc,
    const __half* __restrict__ H, const float* __restrict__ AS,
    const float* __restrict__ AD, const float* __restrict__ bias, int N,
    float* __restrict__ OUT) {
  int t = threadIdx.x;
  int wid = t >> 6;
  int half = (t >> 5) & 1;
  int ll = t & 31;                       // lane within half-wave
  int n = blockIdx.x * 8 + wid * 2 + half;

  constexpr int G = 64 / HEADS;          // channels per head
  int head = (2 * ll) / G;               // both channels in same head (G>=2)

  int rs = 0, re = 0;
  float ad = 0.f;
  if (n < N) {
    rs = row_start[n];
    re = row_start[n + 1];
    ad = AD[(size_t)n * HEADS + head];
  }
  int deg = re - rs;
  int degO = __shfl_xor(deg, 32, 64);    // other half's degree
  int degmax = max(deg, degO);

  const __half2* H2 = reinterpret_cast<const __half2*>(H);

  float m = -1e30f, denom = 0.f, ax = 0.f, ay = 0.f;
  for (int i = 0; i < degmax; ++i) {
    if (i < deg) {
      int s = esrc[rs + i];
      float e = AS[(unsigned)s * HEADS + head] + ad;
      e = e > 0.f ? e : 0.2f * e;
      float2 hf = __half22float2(H2[(unsigned)s * 32u + (unsigned)ll]);
      float mn = fmaxf(m, e);
      float sc = __expf(m - mn);
      float wg = __expf(e - mn);
      denom = fmaf(denom, sc, wg);
      ax = fmaf(ax, sc, wg * hf.x);
      ay = fmaf(ay, sc, wg * hf.y);
      m = mn;
    }
  }

  if (n >= N) return;

  float2 b2 = reinterpret_cast<const float2*>(bias)[ll];
  float inv = 1.f / (denom + 1e-16f);
  float vx = ax * inv + b2.x;
  float vy = ay * inv + b2.y;
  float2* OUT2 = reinterpret_cast<float2*>(OUT);
  if (FINAL) {
    float ss = vx * vx + vy * vy;
#pragma unroll
    for (int off = 1; off < 32; off <<= 1) ss += __shfl_xor(ss, off, 32);
    float rn = 1.f / fmaxf(sqrtf(ss), 1e-12f);
    OUT2[(size_t)n * 32 + ll] = make_float2(vx * rn, vy * rn);
  } else {
    vx = vx > 0.f ? vx : expm1f(vx);
    vy = vy > 0.f ? vy : expm1f(vy);
    OUT2[(size_t)n * 32 + ll] = make_float2(vx, vy);
  }
}

// ---------------- launch ----------------

extern "C" void kernel_launch(void* const* d_in, const int* in_sizes, int n_in,
                              void* d_out, int out_size, void* d_ws,
                              size_t ws_size, hipStream_t stream) {
  const int* ei = (const int*)d_in[0];          // [2, E]
  const float* emb = (const float*)d_in[1];     // [N, 64]
  const float* W1 = (const float*)d_in[2];
  const float* as1 = (const float*)d_in[3];
  const float* ad1 = (const float*)d_in[4];
  const float* b1 = (const float*)d_in[5];
  const float* W2 = (const float*)d_in[6];
  const float* as2 = (const float*)d_in[7];
  const float* ad2 = (const float*)d_in[8];
  const float* b2 = (const float*)d_in[9];
  float* out = (float*)d_out;

  int E = in_sizes[0] / 2;
  int N = in_sizes[1] / FDIM;
  int Etot = E + N;
  int NB = (N + BMASK) >> BSHIFT;           // buckets of 512 nodes (<=512)
  int nTiles = (Etot + EDGE_TILE - 1) / EDGE_TILE;

  char* ws = (char*)d_ws;
  size_t off = 0;
  auto alloc = [&](size_t bytes) -> void* {
    void* p = ws + off;
    off += (bytes + 255) & ~(size_t)255;
    return p;
  };
  int* gbhist = (int*)alloc((size_t)NB * sizeof(int));
  int* boff = (int*)alloc((size_t)(NB + 1) * sizeof(int));
  int* bcur = (int*)alloc((size_t)NB * sizeof(int));
  unsigned* bpacked = (unsigned*)alloc((size_t)Etot * sizeof(unsigned));
  int* row_start = (int*)alloc((size_t)(N + 1) * sizeof(int));
  int* esrc = (int*)alloc((size_t)Etot * sizeof(int));
  __half* hbuf = (__half*)alloc((size_t)N * FDIM * sizeof(__half));
  float* xbuf = (float*)alloc((size_t)N * FDIM * sizeof(float));
  float* AS = (float*)alloc((size_t)N * 4 * sizeof(float));
  float* AD = (float*)alloc((size_t)N * 4 * sizeof(float));

  hipMemsetAsync(gbhist, 0, (size_t)NB * sizeof(int), stream);
  tile_hist_kernel<<<nTiles, 256, 0, stream>>>(ei, E, Etot, NB, gbhist);
  bscan_kernel<<<1, 256, 0, stream>>>(gbhist, NB, Etot, boff, bcur);
  tile_scatter_kernel<<<nTiles, 256, 0, stream>>>(ei, E, Etot, NB, bcur, bpacked);
  bucket_csr_kernel<<<NB, 256, 0, stream>>>(bpacked, boff, N, NB, Etot,
                                            row_start, esrc);

  int ga = (N + 7) / 8;  // aggregate: 8 nodes per block (4 waves x 2)
  // Layer 1: GATConv(64 -> 16, heads=4, concat) + bias + ELU
  gemm_alpha_kernel<4><<<2048, 256, 0, stream>>>(emb, W1, as1, ad1, N, hbuf, AS, AD);
  aggregate_kernel<4, false><<<ga, 256, 0, stream>>>(row_start, esrc, hbuf, AS, AD, b1, N, xbuf);
  // Layer 2: GATConv(64 -> 64, heads=1) + bias + L2 normalize
  gemm_alpha_kernel<1><<<2048, 256, 0, stream>>>(xbuf, W2, as2, ad2, N, hbuf, AS, AD);
  aggregate_kernel<1, true><<<ga, 256, 0, stream>>>(row_start, esrc, hbuf, AS, AD, b2, N, out);
}

// Round 7
// 186.468 us; speedup vs baseline: 4.2987x; 1.4319x over previous
//
#include <hip/hip_runtime.h>
#include <hip/hip_fp16.h>
#include <math.h>

// GAT 2-layer forward on MI355X.
// CSR build: tile-binned counting sort (LDS-only per-edge atomics).
// Per layer:
//   gemm_alpha: h = x@W; x-row via SCALAR loads, 8 indep fma chains, h in FP16
//   aggregate:  wave = 2 dst nodes, lane = channel-pair (__half2 gathers),
//               NO-max softmax (shift-invariant, logits tiny), 4x-unrolled
//               edge loop with 4 independent accumulators for MLP.

constexpr int FDIM = 64;
constexpr int BSHIFT = 9;                 // 512 nodes per bucket
constexpr int BMASK = (1 << BSHIFT) - 1;  // 511
constexpr int EDGE_TILE = 4096;           // edges per phase-A block

// ---------------- CSR build ----------------

__global__ __launch_bounds__(256) void tile_hist_kernel(
    const int* __restrict__ ei, int E, int Etot, int NB,
    int* __restrict__ gbhist) {
  __shared__ int hist[512];
  int t = threadIdx.x;
  for (int b = t; b < NB; b += 256) hist[b] = 0;
  __syncthreads();
  int i0 = blockIdx.x * EDGE_TILE;
  int iend = min(i0 + EDGE_TILE, Etot);
  for (int i = i0 + t; i < iend; i += 256) {
    int dst = (i < E) ? ei[E + i] : (i - E);  // self-loops appended
    atomicAdd(&hist[dst >> BSHIFT], 1);
  }
  __syncthreads();
  for (int b = t; b < NB; b += 256)
    if (hist[b]) atomicAdd(&gbhist[b], hist[b]);
}

__global__ __launch_bounds__(256) void bscan_kernel(
    const int* __restrict__ gbhist, int NB, int Etot,
    int* __restrict__ boff, int* __restrict__ bcur) {
  int t = threadIdx.x;
  int v = (t < NB) ? gbhist[t] : 0;
  int lane = t & 63, w = t >> 6;
  int x = v;
#pragma unroll
  for (int off = 1; off < 64; off <<= 1) {
    int u = __shfl_up(x, off, 64);
    if (lane >= off) x += u;
  }
  __shared__ int wsum[4];
  if (lane == 63) wsum[w] = x;
  __syncthreads();
  int add = 0;
#pragma unroll
  for (int k = 0; k < 4; ++k) add += (k < w) ? wsum[k] : 0;
  int incl = x + add;
  if (t < NB) {
    boff[t] = incl - v;
    bcur[t] = incl - v;
  }
  if (t == 0) boff[NB] = Etot;
}

__global__ __launch_bounds__(256) void tile_scatter_kernel(
    const int* __restrict__ ei, int E, int Etot, int NB,
    int* __restrict__ bcur, unsigned* __restrict__ bpacked) {
  __shared__ int hist[512];
  __shared__ int cur[512];
  int t = threadIdx.x;
  for (int b = t; b < NB; b += 256) hist[b] = 0;
  __syncthreads();
  int i0 = blockIdx.x * EDGE_TILE;
  int iend = min(i0 + EDGE_TILE, Etot);
  for (int i = i0 + t; i < iend; i += 256) {
    int dst = (i < E) ? ei[E + i] : (i - E);
    atomicAdd(&hist[dst >> BSHIFT], 1);
  }
  __syncthreads();
  for (int b = t; b < NB; b += 256)
    cur[b] = hist[b] ? atomicAdd(&bcur[b], hist[b]) : 0;
  __syncthreads();
  for (int i = i0 + t; i < iend; i += 256) {
    int src, dst;
    if (i < E) { src = ei[i]; dst = ei[E + i]; }
    else       { src = i - E; dst = i - E; }
    int pos = atomicAdd(&cur[dst >> BSHIFT], 1);
    bpacked[pos] = ((unsigned)src << BSHIFT) | (unsigned)(dst & BMASK);
  }
}

__global__ __launch_bounds__(256) void bucket_csr_kernel(
    const unsigned* __restrict__ bpacked, const int* __restrict__ boff,
    int N, int NB, int Etot,
    int* __restrict__ row_start, int* __restrict__ esrc) {
  __shared__ int hist[512];
  __shared__ int excl[512];
  __shared__ int cur[512];
  int b = blockIdx.x;
  int t = threadIdx.x;
  int base = boff[b];
  int end = boff[b + 1];
  hist[t] = 0;
  hist[256 + t] = 0;
  __syncthreads();
  for (int i = base + t; i < end; i += 256)
    atomicAdd(&hist[bpacked[i] & (unsigned)BMASK], 1);
  __syncthreads();
  int h0 = hist[2 * t], h1 = hist[2 * t + 1];
  int s = h0 + h1;
  int lane = t & 63, w = t >> 6;
  int x = s;
#pragma unroll
  for (int off = 1; off < 64; off <<= 1) {
    int u = __shfl_up(x, off, 64);
    if (lane >= off) x += u;
  }
  __shared__ int wsum[4];
  if (lane == 63) wsum[w] = x;
  __syncthreads();
  int add = 0;
#pragma unroll
  for (int k = 0; k < 4; ++k) add += (k < w) ? wsum[k] : 0;
  int e0 = x + add - s;
  excl[2 * t] = e0;
  excl[2 * t + 1] = e0 + h0;
  cur[2 * t] = e0;
  cur[2 * t + 1] = e0 + h0;
  __syncthreads();
  int node0 = b << BSHIFT;
#pragma unroll
  for (int k = 0; k < 2; ++k) {
    int slot = k * 256 + t;
    int node = node0 + slot;
    if (node < N) row_start[node] = base + excl[slot];
  }
  if (b == NB - 1 && t == 0) row_start[N] = Etot;
  for (int i = base + t; i < end; i += 256) {
    unsigned p = bpacked[i];
    int pos = base + atomicAdd(&cur[p & (unsigned)BMASK], 1);
    esrc[pos] = (int)(p >> BSHIFT);
  }
}

// ---------------- GEMM (x @ W) + attention logits ----------------

template <int HEADS>
__global__ __launch_bounds__(256) void gemm_alpha_kernel(
    const float* __restrict__ X, const float* __restrict__ W,
    const float* __restrict__ a_s, const float* __restrict__ a_d, int N,
    __half* __restrict__ H, float* __restrict__ AS, float* __restrict__ AD) {
  int lane = threadIdx.x & 63;
  int gwave = (blockIdx.x * 256 + threadIdx.x) >> 6;
  int nwaves = gridDim.x * 4;

  float w[FDIM];
#pragma unroll
  for (int k = 0; k < FDIM; ++k) w[k] = W[k * FDIM + lane];
  float as_l = a_s[lane];
  float ad_l = a_d[lane];
  constexpr int G = 64 / HEADS;

  for (int n = gwave * 2; n < N; n += nwaves * 2) {
    int nu = __builtin_amdgcn_readfirstlane(n);
    const float* xa = X + (size_t)nu * FDIM;
    bool twob = (nu + 1) < N;
    const float* xb = twob ? (xa + FDIM) : xa;

    float a0 = 0.f, a1 = 0.f, a2 = 0.f, a3 = 0.f;
    float c0 = 0.f, c1 = 0.f, c2 = 0.f, c3 = 0.f;
#pragma unroll
    for (int k = 0; k < FDIM; k += 4) {
      a0 = fmaf(xa[k + 0], w[k + 0], a0);
      a1 = fmaf(xa[k + 1], w[k + 1], a1);
      a2 = fmaf(xa[k + 2], w[k + 2], a2);
      a3 = fmaf(xa[k + 3], w[k + 3], a3);
      c0 = fmaf(xb[k + 0], w[k + 0], c0);
      c1 = fmaf(xb[k + 1], w[k + 1], c1);
      c2 = fmaf(xb[k + 2], w[k + 2], c2);
      c3 = fmaf(xb[k + 3], w[k + 3], c3);
    }
    float ha = (a0 + a1) + (a2 + a3);
    float hb = (c0 + c1) + (c2 + c3);

    H[(size_t)nu * FDIM + lane] = __float2half(ha);
    if (twob) H[(size_t)(nu + 1) * FDIM + lane] = __float2half(hb);

    float tsa = ha * as_l, tda = ha * ad_l;
    float tsb = hb * as_l, tdb = hb * ad_l;
#pragma unroll
    for (int off = 1; off < G; off <<= 1) {
      tsa += __shfl_xor(tsa, off, 64);
      tda += __shfl_xor(tda, off, 64);
      tsb += __shfl_xor(tsb, off, 64);
      tdb += __shfl_xor(tdb, off, 64);
    }
    if ((lane & (G - 1)) == 0) {
      int head = lane / G;
      AS[(size_t)nu * HEADS + head] = tsa;
      AD[(size_t)nu * HEADS + head] = tda;
      if (twob) {
        AS[(size_t)(nu + 1) * HEADS + head] = tsb;
        AD[(size_t)(nu + 1) * HEADS + head] = tdb;
      }
    }
  }
}

// ---------------- no-max softmax aggregation, 4x unrolled ----------------
// Wave = 2 dst nodes (lanes 0-31 node A, lanes 32-63 node B).
// Lane owns channel pair (2c, 2c+1) as __half2; accumulate fp32.
// Softmax without max-subtraction (shift-invariant; logits are O(1), fp32
// exp is safe). 4 independent accumulator sets -> 8 gathers in flight.

template <int HEADS, bool FINAL>
__global__ __launch_bounds__(256) void aggregate_kernel(
    const int* __restrict__ row_start, const int* __restrict__ esrc,
    const __half* __restrict__ H, const float* __restrict__ AS,
    const float* __restrict__ AD, const float* __restrict__ bias, int N,
    float* __restrict__ OUT) {
  int t = threadIdx.x;
  int wid = t >> 6;
  int half = (t >> 5) & 1;
  int ll = t & 31;                       // lane within half-wave
  int n = blockIdx.x * 8 + wid * 2 + half;

  constexpr int G = 64 / HEADS;          // channels per head
  int head = (2 * ll) / G;               // both channels in same head (G>=2)

  int rs = 0, re = 0;
  float ad = 0.f;
  if (n < N) {
    rs = row_start[n];
    re = row_start[n + 1];
    ad = AD[(size_t)n * HEADS + head];
  }
  int deg = re - rs;
  int degO = __shfl_xor(deg, 32, 64);    // other half's degree
  int degmax = max(deg, degO);

  const __half2* H2 = reinterpret_cast<const __half2*>(H);

  float d[4] = {0.f, 0.f, 0.f, 0.f};
  float ax[4] = {0.f, 0.f, 0.f, 0.f};
  float ay[4] = {0.f, 0.f, 0.f, 0.f};

  for (int i = 0; i < degmax; i += 4) {
    int sv[4];
#pragma unroll
    for (int k = 0; k < 4; ++k) {
      int o = min(i + k, deg - 1);
      o = max(o, 0);                    // deg==0 guard (inactive node)
      sv[k] = esrc[rs + o];
    }
    float ev[4];
    __half2 hv[4];
#pragma unroll
    for (int k = 0; k < 4; ++k) {
      ev[k] = AS[(unsigned)sv[k] * HEADS + (unsigned)head];
      hv[k] = H2[(unsigned)sv[k] * 32u + (unsigned)ll];
    }
#pragma unroll
    for (int k = 0; k < 4; ++k) {
      float e = ev[k] + ad;
      e = fmaxf(e, 0.2f * e);           // LeakyReLU(0.2)
      float wg = (i + k < deg) ? __expf(e) : 0.f;
      float2 hf = __half22float2(hv[k]);
      d[k] += wg;
      ax[k] = fmaf(wg, hf.x, ax[k]);
      ay[k] = fmaf(wg, hf.y, ay[k]);
    }
  }

  if (n >= N) return;

  float denom = (d[0] + d[1]) + (d[2] + d[3]);
  float axs = (ax[0] + ax[1]) + (ax[2] + ax[3]);
  float ays = (ay[0] + ay[1]) + (ay[2] + ay[3]);

  float2 b2 = reinterpret_cast<const float2*>(bias)[ll];
  float inv = 1.f / (denom + 1e-16f);
  float vx = axs * inv + b2.x;
  float vy = ays * inv + b2.y;
  float2* OUT2 = reinterpret_cast<float2*>(OUT);
  if (FINAL) {
    float ss = vx * vx + vy * vy;
#pragma unroll
    for (int off = 1; off < 32; off <<= 1) ss += __shfl_xor(ss, off, 32);
    float rn = 1.f / fmaxf(sqrtf(ss), 1e-12f);
    OUT2[(size_t)n * 32 + ll] = make_float2(vx * rn, vy * rn);
  } else {
    vx = vx > 0.f ? vx : expm1f(vx);
    vy = vy > 0.f ? vy : expm1f(vy);
    OUT2[(size_t)n * 32 + ll] = make_float2(vx, vy);
  }
}

// ---------------- launch ----------------

extern "C" void kernel_launch(void* const* d_in, const int* in_sizes, int n_in,
                              void* d_out, int out_size, void* d_ws,
                              size_t ws_size, hipStream_t stream) {
  const int* ei = (const int*)d_in[0];          // [2, E]
  const float* emb = (const float*)d_in[1];     // [N, 64]
  const float* W1 = (const float*)d_in[2];
  const float* as1 = (const float*)d_in[3];
  const float* ad1 = (const float*)d_in[4];
  const float* b1 = (const float*)d_in[5];
  const float* W2 = (const float*)d_in[6];
  const float* as2 = (const float*)d_in[7];
  const float* ad2 = (const float*)d_in[8];
  const float* b2 = (const float*)d_in[9];
  float* out = (float*)d_out;

  int E = in_sizes[0] / 2;
  int N = in_sizes[1] / FDIM;
  int Etot = E + N;
  int NB = (N + BMASK) >> BSHIFT;           // buckets of 512 nodes
  int nTiles = (Etot + EDGE_TILE - 1) / EDGE_TILE;

  char* ws = (char*)d_ws;
  size_t off = 0;
  auto alloc = [&](size_t bytes) -> void* {
    void* p = ws + off;
    off += (bytes + 255) & ~(size_t)255;
    return p;
  };
  int* gbhist = (int*)alloc((size_t)NB * sizeof(int));
  int* boff = (int*)alloc((size_t)(NB + 1) * sizeof(int));
  int* bcur = (int*)alloc((size_t)NB * sizeof(int));
  unsigned* bpacked = (unsigned*)alloc((size_t)Etot * sizeof(unsigned));
  int* row_start = (int*)alloc((size_t)(N + 1) * sizeof(int));
  int* esrc = (int*)alloc((size_t)Etot * sizeof(int));
  __half* hbuf = (__half*)alloc((size_t)N * FDIM * sizeof(__half));
  float* xbuf = (float*)alloc((size_t)N * FDIM * sizeof(float));
  float* AS = (float*)alloc((size_t)N * 4 * sizeof(float));
  float* AD = (float*)alloc((size_t)N * 4 * sizeof(float));

  hipMemsetAsync(gbhist, 0, (size_t)NB * sizeof(int), stream);
  tile_hist_kernel<<<nTiles, 256, 0, stream>>>(ei, E, Etot, NB, gbhist);
  bscan_kernel<<<1, 256, 0, stream>>>(gbhist, NB, Etot, boff, bcur);
  tile_scatter_kernel<<<nTiles, 256, 0, stream>>>(ei, E, Etot, NB, bcur, bpacked);
  bucket_csr_kernel<<<NB, 256, 0, stream>>>(bpacked, boff, N, NB, Etot,
                                            row_start, esrc);

  int ga = (N + 7) / 8;  // aggregate: 8 nodes per block (4 waves x 2)
  // Layer 1: GATConv(64 -> 16, heads=4, concat) + bias + ELU
  gemm_alpha_kernel<4><<<2048, 256, 0, stream>>>(emb, W1, as1, ad1, N, hbuf, AS, AD);
  aggregate_kernel<4, false><<<ga, 256, 0, stream>>>(row_start, esrc, hbuf, AS, AD, b1, N, xbuf);
  // Layer 2: GATConv(64 -> 64, heads=1) + bias + L2 normalize
  gemm_alpha_kernel<1><<<2048, 256, 0, stream>>>(xbuf, W2, as2, ad2, N, hbuf, AS, AD);
  aggregate_kernel<1, true><<<ga, 256, 0, stream>>>(row_start, esrc, hbuf, AS, AD, b2, N, out);
}

// Round 8
// 155.024 us; speedup vs baseline: 5.1707x; 1.2028x over previous
//
#include <hip/hip_runtime.h>
#include <hip/hip_fp16.h>
#include <math.h>

// GAT 2-layer forward on MI355X.
// CSR build: tile-binned counting sort (LDS-only per-edge atomics).
// Per layer:
//   mfma_gemm: h = x@W via mfma_f32_16x16x32_f16 (64-row tiles, LDS-staged
//              fp16 X and W^T, pad-72 stride), fused alpha_s/alpha_d epilogue.
//   aggregate: wave = 2 dst nodes, lane = channel-pair (__half2 gathers),
//              no-max softmax, 4x-unrolled edge loop. Layer-1 output fp16.

constexpr int FDIM = 64;
constexpr int BSHIFT = 9;                 // 512 nodes per bucket
constexpr int BMASK = (1 << BSHIFT) - 1;  // 511
constexpr int EDGE_TILE = 4096;           // edges per phase-A block

using f16 = _Float16;
typedef f16 f16x8 __attribute__((ext_vector_type(8)));
typedef f16 f16x4 __attribute__((ext_vector_type(4)));
typedef float f32x4 __attribute__((ext_vector_type(4)));

// ---------------- small utility ----------------

__global__ void zero_kernel(int* __restrict__ p, int n) {
  int i = blockIdx.x * blockDim.x + threadIdx.x;
  if (i < n) p[i] = 0;
}

// ---------------- CSR build ----------------

__global__ __launch_bounds__(256) void tile_hist_kernel(
    const int* __restrict__ ei, int E, int Etot, int NB,
    int* __restrict__ gbhist) {
  __shared__ int hist[512];
  int t = threadIdx.x;
  for (int b = t; b < NB; b += 256) hist[b] = 0;
  __syncthreads();
  int i0 = blockIdx.x * EDGE_TILE;
  int iend = min(i0 + EDGE_TILE, Etot);
  for (int i = i0 + t; i < iend; i += 256) {
    int dst = (i < E) ? ei[E + i] : (i - E);  // self-loops appended
    atomicAdd(&hist[dst >> BSHIFT], 1);
  }
  __syncthreads();
  for (int b = t; b < NB; b += 256)
    if (hist[b]) atomicAdd(&gbhist[b], hist[b]);
}

__global__ __launch_bounds__(256) void bscan_kernel(
    const int* __restrict__ gbhist, int NB, int Etot,
    int* __restrict__ boff, int* __restrict__ bcur) {
  int t = threadIdx.x;
  int v = (t < NB) ? gbhist[t] : 0;
  int lane = t & 63, w = t >> 6;
  int x = v;
#pragma unroll
  for (int off = 1; off < 64; off <<= 1) {
    int u = __shfl_up(x, off, 64);
    if (lane >= off) x += u;
  }
  __shared__ int wsum[4];
  if (lane == 63) wsum[w] = x;
  __syncthreads();
  int add = 0;
#pragma unroll
  for (int k = 0; k < 4; ++k) add += (k < w) ? wsum[k] : 0;
  int incl = x + add;
  if (t < NB) {
    boff[t] = incl - v;
    bcur[t] = incl - v;
  }
  if (t == 0) boff[NB] = Etot;
}

__global__ __launch_bounds__(256) void tile_scatter_kernel(
    const int* __restrict__ ei, int E, int Etot, int NB,
    int* __restrict__ bcur, unsigned* __restrict__ bpacked) {
  __shared__ int hist[512];
  __shared__ int cur[512];
  int t = threadIdx.x;
  for (int b = t; b < NB; b += 256) hist[b] = 0;
  __syncthreads();
  int i0 = blockIdx.x * EDGE_TILE;
  int iend = min(i0 + EDGE_TILE, Etot);
  for (int i = i0 + t; i < iend; i += 256) {
    int dst = (i < E) ? ei[E + i] : (i - E);
    atomicAdd(&hist[dst >> BSHIFT], 1);
  }
  __syncthreads();
  for (int b = t; b < NB; b += 256)
    cur[b] = hist[b] ? atomicAdd(&bcur[b], hist[b]) : 0;
  __syncthreads();
  for (int i = i0 + t; i < iend; i += 256) {
    int src, dst;
    if (i < E) { src = ei[i]; dst = ei[E + i]; }
    else       { src = i - E; dst = i - E; }
    int pos = atomicAdd(&cur[dst >> BSHIFT], 1);
    bpacked[pos] = ((unsigned)src << BSHIFT) | (unsigned)(dst & BMASK);
  }
}

__global__ __launch_bounds__(256) void bucket_csr_kernel(
    const unsigned* __restrict__ bpacked, const int* __restrict__ boff,
    int N, int NB, int Etot,
    int* __restrict__ row_start, int* __restrict__ esrc) {
  __shared__ int hist[512];
  __shared__ int excl[512];
  __shared__ int cur[512];
  int b = blockIdx.x;
  int t = threadIdx.x;
  int base = boff[b];
  int end = boff[b + 1];
  hist[t] = 0;
  hist[256 + t] = 0;
  __syncthreads();
  for (int i = base + t; i < end; i += 256)
    atomicAdd(&hist[bpacked[i] & (unsigned)BMASK], 1);
  __syncthreads();
  int h0 = hist[2 * t], h1 = hist[2 * t + 1];
  int s = h0 + h1;
  int lane = t & 63, w = t >> 6;
  int x = s;
#pragma unroll
  for (int off = 1; off < 64; off <<= 1) {
    int u = __shfl_up(x, off, 64);
    if (lane >= off) x += u;
  }
  __shared__ int wsum[4];
  if (lane == 63) wsum[w] = x;
  __syncthreads();
  int add = 0;
#pragma unroll
  for (int k = 0; k < 4; ++k) add += (k < w) ? wsum[k] : 0;
  int e0 = x + add - s;
  excl[2 * t] = e0;
  excl[2 * t + 1] = e0 + h0;
  cur[2 * t] = e0;
  cur[2 * t + 1] = e0 + h0;
  __syncthreads();
  int node0 = b << BSHIFT;
#pragma unroll
  for (int k = 0; k < 2; ++k) {
    int slot = k * 256 + t;
    int node = node0 + slot;
    if (node < N) row_start[node] = base + excl[slot];
  }
  if (b == NB - 1 && t == 0) row_start[N] = Etot;
  for (int i = base + t; i < end; i += 256) {
    unsigned p = bpacked[i];
    int pos = base + atomicAdd(&cur[p & (unsigned)BMASK], 1);
    esrc[pos] = (int)(p >> BSHIFT);
  }
}

// ---------------- MFMA GEMM (x @ W) + attention logits ----------------
// Block = 64 rows x 64 cols, K=64. 4 waves, each wave: 16 rows x 64 cols via
// 4 col-tiles x 2 mfma_f32_16x16x32_f16. LDS: Xs[64][72] fp16, Wt[64][72]
// fp16 (W transposed; pad-72 -> 2-way bank aliasing = free).
// A-frag: lane holds A[row=l&15][k=(l>>4)*8+j]. B-frag: B[k=(l>>4)*8+j][col=l&15]
// read from Wt[col][k]. C: col=l&15, row=(l>>4)*4+reg (HW-verified layout).
// Epilogue: H fp16 store + alpha_s/alpha_d via 4-step shfl reduce over l&15.

template <int HEADS, typename IN>
__global__ __launch_bounds__(256) void mfma_gemm_kernel(
    const IN* __restrict__ X, const float* __restrict__ W,
    const float* __restrict__ a_s, const float* __restrict__ a_d, int N,
    __half* __restrict__ H, float* __restrict__ AS, float* __restrict__ AD) {
  __shared__ f16 Xs[64 * 72];
  __shared__ f16 Wt[64 * 72];
  int t = threadIdx.x;
  int row0 = blockIdx.x * 64;

  // stage Wt[col][k] = W[k][col], fp32 -> fp16
#pragma unroll
  for (int i = 0; i < 16; ++i) {
    int idx = i * 256 + t;
    int k = idx >> 6, c = idx & 63;
    Wt[c * 72 + k] = (f16)W[idx];
  }
  // stage Xs[r][k]
  if constexpr (sizeof(IN) == 4) {
#pragma unroll
    for (int i = 0; i < 4; ++i) {
      int idx = (i * 256 + t) * 4;
      int r = idx >> 6, k = idx & 63;
      int rg = min(row0 + r, N - 1);
      float4 f = *reinterpret_cast<const float4*>(
          reinterpret_cast<const float*>(X) + (size_t)rg * 64 + k);
      f16x4 v = {(f16)f.x, (f16)f.y, (f16)f.z, (f16)f.w};
      *reinterpret_cast<f16x4*>(&Xs[r * 72 + k]) = v;
    }
  } else {
#pragma unroll
    for (int i = 0; i < 2; ++i) {
      int idx = (i * 256 + t) * 8;
      int r = idx >> 6, k = idx & 63;
      int rg = min(row0 + r, N - 1);
      f16x8 v = *reinterpret_cast<const f16x8*>(
          reinterpret_cast<const f16*>(X) + (size_t)rg * 64 + k);
      *reinterpret_cast<f16x8*>(&Xs[r * 72 + k]) = v;
    }
  }
  __syncthreads();

  int lane = t & 63, wid = t >> 6;
  int m0 = wid * 16;
  int li = lane & 15, lk = lane >> 4;
  int ko = lk * 8;

  f16x8 a_lo = *reinterpret_cast<const f16x8*>(&Xs[(m0 + li) * 72 + ko]);
  f16x8 a_hi = *reinterpret_cast<const f16x8*>(&Xs[(m0 + li) * 72 + 32 + ko]);

  f32x4 acc[4];
  float asc[4], adc[4];
#pragma unroll
  for (int q = 0; q < 4; ++q) {
    acc[q] = (f32x4){0.f, 0.f, 0.f, 0.f};
    asc[q] = a_s[q * 16 + li];
    adc[q] = a_d[q * 16 + li];
  }
#pragma unroll
  for (int q = 0; q < 4; ++q) {
    int c0 = q * 16 + li;
    f16x8 b_lo = *reinterpret_cast<const f16x8*>(&Wt[c0 * 72 + ko]);
    f16x8 b_hi = *reinterpret_cast<const f16x8*>(&Wt[c0 * 72 + 32 + ko]);
    acc[q] = __builtin_amdgcn_mfma_f32_16x16x32_f16(a_lo, b_lo, acc[q], 0, 0, 0);
    acc[q] = __builtin_amdgcn_mfma_f32_16x16x32_f16(a_hi, b_hi, acc[q], 0, 0, 0);
  }

  // H store: C row = lk*4 + r (within 16-tile), col = q*16 + li
  int rbase = row0 + m0 + lk * 4;
#pragma unroll
  for (int r = 0; r < 4; ++r) {
    int grow = rbase + r;
    if (grow < N) {
#pragma unroll
      for (int q = 0; q < 4; ++q)
        H[(size_t)grow * 64 + q * 16 + li] = __float2half((float)acc[q][r]);
    }
  }

  // alpha epilogue
  if constexpr (HEADS == 4) {
    float ps[4][4], pd[4][4];
#pragma unroll
    for (int q = 0; q < 4; ++q)
#pragma unroll
      for (int r = 0; r < 4; ++r) {
        ps[q][r] = (float)acc[q][r] * asc[q];
        pd[q][r] = (float)acc[q][r] * adc[q];
      }
#pragma unroll
    for (int off = 1; off < 16; off <<= 1)
#pragma unroll
      for (int q = 0; q < 4; ++q)
#pragma unroll
        for (int r = 0; r < 4; ++r) {
          ps[q][r] += __shfl_xor(ps[q][r], off, 64);
          pd[q][r] += __shfl_xor(pd[q][r], off, 64);
        }
    if (li == 0) {
#pragma unroll
      for (int r = 0; r < 4; ++r) {
        int grow = rbase + r;
        if (grow < N) {
#pragma unroll
          for (int q = 0; q < 4; ++q) {
            AS[(size_t)grow * 4 + q] = ps[q][r];
            AD[(size_t)grow * 4 + q] = pd[q][r];
          }
        }
      }
    }
  } else {
    float ps[4], pd[4];
#pragma unroll
    for (int r = 0; r < 4; ++r) {
      ps[r] = 0.f; pd[r] = 0.f;
#pragma unroll
      for (int q = 0; q < 4; ++q) {
        ps[r] = fmaf((float)acc[q][r], asc[q], ps[r]);
        pd[r] = fmaf((float)acc[q][r], adc[q], pd[r]);
      }
    }
#pragma unroll
    for (int off = 1; off < 16; off <<= 1)
#pragma unroll
      for (int r = 0; r < 4; ++r) {
        ps[r] += __shfl_xor(ps[r], off, 64);
        pd[r] += __shfl_xor(pd[r], off, 64);
      }
    if (li == 0) {
#pragma unroll
      for (int r = 0; r < 4; ++r) {
        int grow = rbase + r;
        if (grow < N) { AS[grow] = ps[r]; AD[grow] = pd[r]; }
      }
    }
  }
}

// ---------------- no-max softmax aggregation, 4x unrolled ----------------
// Wave = 2 dst nodes; lane owns channel pair as __half2; fp32 accumulate.
// FINAL=false: +bias, ELU, fp16 out.  FINAL=true: +bias, L2-normalize, fp32.

template <int HEADS, bool FINAL, typename OUTT>
__global__ __launch_bounds__(256) void aggregate_kernel(
    const int* __restrict__ row_start, const int* __restrict__ esrc,
    const __half* __restrict__ H, const float* __restrict__ AS,
    const float* __restrict__ AD, const float* __restrict__ bias, int N,
    OUTT* __restrict__ OUT) {
  int t = threadIdx.x;
  int wid = t >> 6;
  int half = (t >> 5) & 1;
  int ll = t & 31;
  int n = blockIdx.x * 8 + wid * 2 + half;

  constexpr int G = 64 / HEADS;
  int head = (2 * ll) / G;

  int rs = 0, re = 0;
  float ad = 0.f;
  if (n < N) {
    rs = row_start[n];
    re = row_start[n + 1];
    ad = AD[(size_t)n * HEADS + head];
  }
  int deg = re - rs;
  int degO = __shfl_xor(deg, 32, 64);
  int degmax = max(deg, degO);

  const __half2* H2 = reinterpret_cast<const __half2*>(H);

  float d[4] = {0.f, 0.f, 0.f, 0.f};
  float ax[4] = {0.f, 0.f, 0.f, 0.f};
  float ay[4] = {0.f, 0.f, 0.f, 0.f};

  for (int i = 0; i < degmax; i += 4) {
    int sv[4];
#pragma unroll
    for (int k = 0; k < 4; ++k) {
      int o = min(i + k, deg - 1);
      o = max(o, 0);
      sv[k] = esrc[rs + o];
    }
    float ev[4];
    __half2 hv[4];
#pragma unroll
    for (int k = 0; k < 4; ++k) {
      ev[k] = AS[(unsigned)sv[k] * HEADS + (unsigned)head];
      hv[k] = H2[(unsigned)sv[k] * 32u + (unsigned)ll];
    }
#pragma unroll
    for (int k = 0; k < 4; ++k) {
      float e = ev[k] + ad;
      e = fmaxf(e, 0.2f * e);           // LeakyReLU(0.2)
      float wg = (i + k < deg) ? __expf(e) : 0.f;
      float2 hf = __half22float2(hv[k]);
      d[k] += wg;
      ax[k] = fmaf(wg, hf.x, ax[k]);
      ay[k] = fmaf(wg, hf.y, ay[k]);
    }
  }

  if (n >= N) return;

  float denom = (d[0] + d[1]) + (d[2] + d[3]);
  float axs = (ax[0] + ax[1]) + (ax[2] + ax[3]);
  float ays = (ay[0] + ay[1]) + (ay[2] + ay[3]);

  float2 b2 = reinterpret_cast<const float2*>(bias)[ll];
  float inv = 1.f / (denom + 1e-16f);
  float vx = axs * inv + b2.x;
  float vy = ays * inv + b2.y;
  if constexpr (FINAL) {
    float ss = vx * vx + vy * vy;
#pragma unroll
    for (int off = 1; off < 32; off <<= 1) ss += __shfl_xor(ss, off, 32);
    float rn = 1.f / fmaxf(sqrtf(ss), 1e-12f);
    float2* OUT2 = reinterpret_cast<float2*>(OUT);
    OUT2[(size_t)n * 32 + ll] = make_float2(vx * rn, vy * rn);
  } else {
    vx = vx > 0.f ? vx : expm1f(vx);
    vy = vy > 0.f ? vy : expm1f(vy);
    __half2* OUT2 = reinterpret_cast<__half2*>(OUT);
    OUT2[(size_t)n * 32 + ll] = __floats2half2_rn(vx, vy);
  }
}

// ---------------- launch ----------------

extern "C" void kernel_launch(void* const* d_in, const int* in_sizes, int n_in,
                              void* d_out, int out_size, void* d_ws,
                              size_t ws_size, hipStream_t stream) {
  const int* ei = (const int*)d_in[0];          // [2, E]
  const float* emb = (const float*)d_in[1];     // [N, 64]
  const float* W1 = (const float*)d_in[2];
  const float* as1 = (const float*)d_in[3];
  const float* ad1 = (const float*)d_in[4];
  const float* b1 = (const float*)d_in[5];
  const float* W2 = (const float*)d_in[6];
  const float* as2 = (const float*)d_in[7];
  const float* ad2 = (const float*)d_in[8];
  const float* b2 = (const float*)d_in[9];
  float* out = (float*)d_out;

  int E = in_sizes[0] / 2;
  int N = in_sizes[1] / FDIM;
  int Etot = E + N;
  int NB = (N + BMASK) >> BSHIFT;           // buckets of 512 nodes
  int nTiles = (Etot + EDGE_TILE - 1) / EDGE_TILE;

  char* ws = (char*)d_ws;
  size_t off = 0;
  auto alloc = [&](size_t bytes) -> void* {
    void* p = ws + off;
    off += (bytes + 255) & ~(size_t)255;
    return p;
  };
  int* gbhist = (int*)alloc((size_t)NB * sizeof(int));
  int* boff = (int*)alloc((size_t)(NB + 1) * sizeof(int));
  int* bcur = (int*)alloc((size_t)NB * sizeof(int));
  unsigned* bpacked = (unsigned*)alloc((size_t)Etot * sizeof(unsigned));
  int* row_start = (int*)alloc((size_t)(N + 1) * sizeof(int));
  int* esrc = (int*)alloc((size_t)Etot * sizeof(int));
  __half* hbuf = (__half*)alloc((size_t)N * FDIM * sizeof(__half));
  __half* xbuf = (__half*)alloc((size_t)N * FDIM * sizeof(__half));
  float* AS = (float*)alloc((size_t)N * 4 * sizeof(float));
  float* AD = (float*)alloc((size_t)N * 4 * sizeof(float));

  zero_kernel<<<(NB + 255) / 256, 256, 0, stream>>>(gbhist, NB);
  tile_hist_kernel<<<nTiles, 256, 0, stream>>>(ei, E, Etot, NB, gbhist);
  bscan_kernel<<<1, 256, 0, stream>>>(gbhist, NB, Etot, boff, bcur);
  tile_scatter_kernel<<<nTiles, 256, 0, stream>>>(ei, E, Etot, NB, bcur, bpacked);
  bucket_csr_kernel<<<NB, 256, 0, stream>>>(bpacked, boff, N, NB, Etot,
                                            row_start, esrc);

  int gm = (N + 63) / 64;   // mfma gemm: 64 rows per block
  int ga = (N + 7) / 8;     // aggregate: 8 nodes per block (4 waves x 2)
  // Layer 1: GATConv(64 -> 16, heads=4, concat) + bias + ELU (fp16 out)
  mfma_gemm_kernel<4, float><<<gm, 256, 0, stream>>>(emb, W1, as1, ad1, N, hbuf, AS, AD);
  aggregate_kernel<4, false, __half><<<ga, 256, 0, stream>>>(row_start, esrc, hbuf, AS, AD, b1, N, xbuf);
  // Layer 2: GATConv(64 -> 64, heads=1) + bias + L2 normalize (fp32 out)
  mfma_gemm_kernel<1, __half><<<gm, 256, 0, stream>>>(xbuf, W2, as2, ad2, N, hbuf, AS, AD);
  aggregate_kernel<1, true, float><<<ga, 256, 0, stream>>>(row_start, esrc, hbuf, AS, AD, b2, N, out);
}